// Round 1
// baseline (2239.014 us; speedup 1.0000x reference)
//
#include <hip/hip_runtime.h>
#include <stdint.h>

// MLA attention, MI355X baseline.
// Stage 1: kv = compressed_kv @ w_up^T  (bf16 MFMA, m97-style 128x128 tile)
// Stage 2: causal flash attention, fp32 vector ALU (correctness-first baseline)

#define Bz 4
#define Sz 1024
#define Hz 16
#define NOPEz 128
#define ROPEz 64
#define VDz 128
#define RANKz 512
#define DQKz 192
#define SCALEf 0.07216878364870323f

typedef __attribute__((ext_vector_type(8))) short bf16x8;
typedef __attribute__((ext_vector_type(4))) float f32x4;

__device__ __forceinline__ unsigned short f2b(float f) {
  union { float f; uint32_t u; } x; x.f = f;
  return (unsigned short)((x.u + 0x7fffu + ((x.u >> 16) & 1u)) >> 16);
}
__device__ __forceinline__ float b2f(unsigned short s) {
  union { uint32_t u; float f; } x; x.u = ((uint32_t)s) << 16;
  return x.f;
}

// ---------------------------------------------------------------- cvt fp32->bf16
__global__ void cvt_bf16_kernel(const float* __restrict__ a, unsigned short* __restrict__ ao,
                                const float* __restrict__ b, unsigned short* __restrict__ bo,
                                int nvec_each) {
  int idx = blockIdx.x * blockDim.x + threadIdx.x;
  const float* s; unsigned short* d; int i;
  if (idx < nvec_each) { s = a; d = ao; i = idx; }
  else                 { s = b; d = bo; i = idx - nvec_each; }
  float4 v = ((const float4*)s)[i];
  ushort4 o = make_ushort4(f2b(v.x), f2b(v.y), f2b(v.z), f2b(v.w));
  ((ushort4*)d)[i] = o;
}

// ---------------------------------------------------------------- stage 1 GEMM
// C[m][n] = sum_k A[m][k] * B[n][k]; A=ckv bf16 [4096][512], B=w_up bf16 [4096][512]
__global__ __launch_bounds__(256)
void gemm_kv_bf16(const unsigned short* __restrict__ A,
                  const unsigned short* __restrict__ Bm,
                  unsigned short* __restrict__ C) {
  __shared__ unsigned short As[128 * 32];
  __shared__ unsigned short Bs[128 * 32];
  const int tid = threadIdx.x;
  const int w = tid >> 6, lane = tid & 63;
  const int wr = w >> 1, wc = w & 1;
  const int row0 = blockIdx.x * 128, col0 = blockIdx.y * 128;
  f32x4 acc[4][4];
#pragma unroll
  for (int m = 0; m < 4; ++m)
#pragma unroll
    for (int n = 0; n < 4; ++n) acc[m][n] = (f32x4){0.f, 0.f, 0.f, 0.f};

  const int rstage = (lane >> 2);
  const int cstage = (lane & 3) * 8;

  for (int kt = 0; kt < RANKz / 32; ++kt) {
    const int k0 = kt * 32;
#pragma unroll
    for (int i = 0; i < 2; ++i) {
      const int chunk = i * 4 + w;               // wave-uniform
      const int r = chunk * 16 + rstage;
      const unsigned short* ga = A  + (size_t)(row0 + r) * RANKz + k0 + cstage;
      const unsigned short* gb = Bm + (size_t)(col0 + r) * RANKz + k0 + cstage;
      // LDS dest is wave-uniform base; HW scatters lane*16B
      __builtin_amdgcn_global_load_lds((const __attribute__((address_space(1))) void*)ga,
                                       (__attribute__((address_space(3))) void*)&As[chunk * 512], 16, 0, 0);
      __builtin_amdgcn_global_load_lds((const __attribute__((address_space(1))) void*)gb,
                                       (__attribute__((address_space(3))) void*)&Bs[chunk * 512], 16, 0, 0);
    }
    __syncthreads();
    const int klo = (lane >> 4) * 8;
    bf16x8 af[4], bfr[4];
#pragma unroll
    for (int m = 0; m < 4; ++m)
      af[m] = *(const bf16x8*)&As[(wr * 64 + m * 16 + (lane & 15)) * 32 + klo];
#pragma unroll
    for (int n = 0; n < 4; ++n)
      bfr[n] = *(const bf16x8*)&Bs[(wc * 64 + n * 16 + (lane & 15)) * 32 + klo];
#pragma unroll
    for (int m = 0; m < 4; ++m)
#pragma unroll
      for (int n = 0; n < 4; ++n)
        acc[m][n] = __builtin_amdgcn_mfma_f32_16x16x32_bf16(af[m], bfr[n], acc[m][n], 0, 0, 0);
    __syncthreads();
  }
  // C/D layout: col = lane&15, row = (lane>>4)*4 + j
  const int cb = col0 + wc * 64 + (lane & 15);
  const int rb = row0 + wr * 64 + (lane >> 4) * 4;
#pragma unroll
  for (int m = 0; m < 4; ++m)
#pragma unroll
    for (int n = 0; n < 4; ++n)
#pragma unroll
      for (int j = 0; j < 4; ++j)
        C[(size_t)(rb + m * 16 + j) * 4096 + (cb + n * 16)] = f2b(acc[m][n][j]);
}

// ---------------------------------------------------------------- stage 2 attention
// grid = (16 q-tiles, 64 b*h). Block = 256 thr = 4 waves, 16 q-rows per wave.
// Lanes own k-columns for scores; (row, d-slice) for PV output accumulation.
__global__ __launch_bounds__(256, 1)
void mla_attn_kernel(const float* __restrict__ q,
                     const unsigned short* __restrict__ kvb,  // [T][16*256] bf16
                     const float* __restrict__ ropek,         // [T][64]
                     float* __restrict__ out) {               // [T][16][128]
  __shared__ float Qs[64][192];            // 49152 B
  __shared__ unsigned short Ks[64][200];   // 25600 B (192 used; stride 200 -> conflict-free b128)
  __shared__ float Vs[64][128];            // 32768 B
  __shared__ float Ps[4][16][65];          // 16640 B  (per-wave P tile)

  const int tid = threadIdx.x;
  const int w = tid >> 6, lane = tid & 63;
  const int qt = blockIdx.x;
  const int bh = blockIdx.y;
  const int bat = bh >> 4, h = bh & 15;
  const int qbase = qt * 64;
  const int tok0 = bat * Sz + qbase;

  { // stage Q once: 64 rows x 192 fp32, 4 threads/row
    const int r = tid >> 2, t4 = tid & 3;
    const float* qp = q + ((size_t)(tok0 + r) * Hz + h) * DQKz;
#pragma unroll
    for (int i = 0; i < 12; ++i) {
      const int c4 = t4 + i * 4;
      *(float4*)&Qs[r][c4 * 4] = *(const float4*)&qp[c4 * 4];
    }
  }

  float m_run[16], l_run[16], accv[32];
#pragma unroll
  for (int r = 0; r < 16; ++r) { m_run[r] = -1e30f; l_run[r] = 0.f; }
#pragma unroll
  for (int i = 0; i < 32; ++i) accv[i] = 0.f;
  const int r_own = lane >> 2;         // output row this lane accumulates
  const int dq = (lane & 3) * 4;       // output d-slice base: d = dq + 16*c + ii

  const int ntiles = qt + 1;
  for (int t = 0; t < ntiles; ++t) {
    __syncthreads();                   // protect LDS from previous iteration's readers
    const int ks0 = t * 64;
    const unsigned short* kvp = kvb + ((size_t)(bat * Sz + ks0) * Hz + h) * 256;
    {
      int idx = tid;
#pragma unroll
      for (int i = 0; i < 4; ++i, idx += 256) {  // K nope: 64 x 128 bf16
        const int r = idx >> 4, c8 = idx & 15;
        *(uint4*)&Ks[r][c8 * 8] = *(const uint4*)&kvp[(size_t)r * 4096 + c8 * 8];
      }
      idx = tid;
#pragma unroll
      for (int i = 0; i < 4; ++i, idx += 256) {  // V: 64 x 128 bf16 -> fp32 LDS
        const int r = idx >> 4, c8 = idx & 15;
        union { uint4 v; unsigned short u[8]; } raw;
        raw.v = *(const uint4*)&kvp[(size_t)r * 4096 + 128 + c8 * 8];
        *(float4*)&Vs[r][c8 * 8]     = make_float4(b2f(raw.u[0]), b2f(raw.u[1]), b2f(raw.u[2]), b2f(raw.u[3]));
        *(float4*)&Vs[r][c8 * 8 + 4] = make_float4(b2f(raw.u[4]), b2f(raw.u[5]), b2f(raw.u[6]), b2f(raw.u[7]));
      }
      idx = tid;
#pragma unroll
      for (int i = 0; i < 4; ++i, idx += 256) {  // rope K: 64 x 64 fp32 -> bf16
        const int r = idx >> 4, c4 = idx & 15;
        float4 v = *(const float4*)&ropek[(size_t)(bat * Sz + ks0 + r) * 64 + c4 * 4];
        ushort4 o = make_ushort4(f2b(v.x), f2b(v.y), f2b(v.z), f2b(v.w));
        *(ushort4*)&Ks[r][128 + c4 * 4] = o;
      }
    }
    __syncthreads();

    // ---- scores: lane owns k = ks0 + lane; 16 q-rows per wave
    float s[16];
#pragma unroll
    for (int r = 0; r < 16; ++r) s[r] = 0.f;
    const unsigned short* krow = &Ks[lane][0];
#pragma unroll 2
    for (int d0 = 0; d0 < 192; d0 += 8) {
      union { uint4 v; unsigned short u[8]; } kraw;
      kraw.v = *(const uint4*)&krow[d0];
      float kf[8];
#pragma unroll
      for (int j = 0; j < 8; ++j) kf[j] = b2f(kraw.u[j]);
#pragma unroll
      for (int r = 0; r < 16; ++r) {
        const float* qrow = &Qs[w * 16 + r][d0];
        float4 qa = *(const float4*)qrow;
        float4 qb = *(const float4*)(qrow + 4);
        s[r] += qa.x * kf[0] + qa.y * kf[1] + qa.z * kf[2] + qa.w * kf[3]
              + qb.x * kf[4] + qb.y * kf[5] + qb.z * kf[6] + qb.w * kf[7];
      }
    }

    // ---- scale + causal mask
    const int ks = ks0 + lane;
    float mx[16];
#pragma unroll
    for (int r = 0; r < 16; ++r) {
      const int qs = qbase + w * 16 + r;
      s[r] = (ks <= qs) ? s[r] * SCALEf : -1e30f;
      mx[r] = s[r];
    }
    // ---- row max (64-lane butterfly)
#pragma unroll
    for (int off = 1; off < 64; off <<= 1)
#pragma unroll
      for (int r = 0; r < 16; ++r) mx[r] = fmaxf(mx[r], __shfl_xor(mx[r], off));

    float p[16], ts[16];
#pragma unroll
    for (int r = 0; r < 16; ++r) {
      const float nm = fmaxf(m_run[r], mx[r]);
      p[r] = __expf(s[r] - nm);
      ts[r] = p[r];
      mx[r] = nm;
    }
#pragma unroll
    for (int off = 1; off < 64; off <<= 1)
#pragma unroll
      for (int r = 0; r < 16; ++r) ts[r] += __shfl_xor(ts[r], off);

    float corr_own = 1.f;
#pragma unroll
    for (int r = 0; r < 16; ++r) {          // static indexing only (no scratch)
      const float c = __expf(m_run[r] - mx[r]);
      l_run[r] = l_run[r] * c + ts[r];
      m_run[r] = mx[r];
      corr_own = (r == r_own) ? c : corr_own;
    }
#pragma unroll
    for (int i = 0; i < 32; ++i) accv[i] *= corr_own;

    // ---- hand P to (row,d)-owners via per-wave LDS
#pragma unroll
    for (int r = 0; r < 16; ++r) Ps[w][r][lane] = p[r];
    const float* pvrow = &Ps[w][r_own][0];   // same-wave DS ordering: write->read safe
#pragma unroll 4
    for (int k = 0; k < 64; ++k) {
      const float pk = pvrow[k];
#pragma unroll
      for (int c = 0; c < 8; ++c) {
        float4 vv = *(const float4*)&Vs[k][dq + 16 * c];
        accv[c * 4 + 0] += pk * vv.x;
        accv[c * 4 + 1] += pk * vv.y;
        accv[c * 4 + 2] += pk * vv.z;
        accv[c * 4 + 3] += pk * vv.w;
      }
    }
  }

  float l_own = 1.f;
#pragma unroll
  for (int r = 0; r < 16; ++r) l_own = (r == r_own) ? l_run[r] : l_own;
  const float inv = 1.0f / l_own;
  const int qs = tok0 + w * 16 + r_own;
  float* op = out + ((size_t)qs * Hz + h) * VDz;
#pragma unroll
  for (int c = 0; c < 8; ++c) {
    float4 o = make_float4(accv[c * 4 + 0] * inv, accv[c * 4 + 1] * inv,
                           accv[c * 4 + 2] * inv, accv[c * 4 + 3] * inv);
    *(float4*)&op[dq + 16 * c] = o;
  }
}

// ---------------------------------------------------------------- launch
extern "C" void kernel_launch(void* const* d_in, const int* in_sizes, int n_in,
                              void* d_out, int out_size, void* d_ws, size_t ws_size,
                              hipStream_t stream) {
  const float* q    = (const float*)d_in[0];
  const float* ckv  = (const float*)d_in[1];
  const float* rope = (const float*)d_in[2];
  const float* wup  = (const float*)d_in[3];
  float* out = (float*)d_out;

  // workspace: ckv bf16 (4MB) | w_up bf16 (4MB) | kv bf16 (32MB)
  unsigned short* ckvb = (unsigned short*)d_ws;
  unsigned short* wupb = ckvb + (size_t)4096 * RANKz;
  unsigned short* kvb  = wupb + (size_t)4096 * RANKz;

  const int nvec = 4096 * RANKz / 4;                 // 524288 float4 per matrix
  cvt_bf16_kernel<<<(2 * nvec) / 256, 256, 0, stream>>>(ckv, ckvb, wup, wupb, nvec);

  dim3 gg(32, 32);
  gemm_kv_bf16<<<gg, 256, 0, stream>>>(ckvb, wupb, kvb);

  dim3 ga(16, 64);
  mla_attn_kernel<<<ga, 256, 0, stream>>>(q, kvb, rope, out);
}

// Round 2
// 140.531 us; speedup vs baseline: 15.9326x; 15.9326x over previous
//
#include <hip/hip_runtime.h>
#include <stdint.h>

// MLA attention, MI355X round 2.
// Stage 1: kv = compressed_kv @ w_up^T  (bf16 MFMA, m97-style 128x128 tile)
// Stage 2: causal flash attention, bf16 MFMA (16x16x32), 4 waves x 32 q-rows,
//          KV tile 64, V transposed in LDS, P via per-wave LDS round-trip.

#define Bz 4
#define Sz 1024
#define Hz 16
#define RANKz 512
#define SCALEf 0.07216878364870323f

typedef __attribute__((ext_vector_type(8))) short bf16x8;
typedef __attribute__((ext_vector_type(4))) float f32x4;

__device__ __forceinline__ unsigned short f2b(float f) {
  union { float f; uint32_t u; } x; x.f = f;
  return (unsigned short)((x.u + 0x7fffu + ((x.u >> 16) & 1u)) >> 16);
}
__device__ __forceinline__ float b2f(unsigned short s) {
  union { uint32_t u; float f; } x; x.u = ((uint32_t)s) << 16;
  return x.f;
}

// ---------------------------------------------------------------- cvt fp32->bf16
__global__ void cvt_bf16_kernel(const float* __restrict__ a, unsigned short* __restrict__ ao,
                                const float* __restrict__ b, unsigned short* __restrict__ bo,
                                int nvec_each) {
  int idx = blockIdx.x * blockDim.x + threadIdx.x;
  const float* s; unsigned short* d; int i;
  if (idx < nvec_each) { s = a; d = ao; i = idx; }
  else                 { s = b; d = bo; i = idx - nvec_each; }
  float4 v = ((const float4*)s)[i];
  ushort4 o = make_ushort4(f2b(v.x), f2b(v.y), f2b(v.z), f2b(v.w));
  ((ushort4*)d)[i] = o;
}

// ---------------------------------------------------------------- stage 1 GEMM
__global__ __launch_bounds__(256)
void gemm_kv_bf16(const unsigned short* __restrict__ A,
                  const unsigned short* __restrict__ Bm,
                  unsigned short* __restrict__ C) {
  __shared__ unsigned short As[128 * 32];
  __shared__ unsigned short Bs[128 * 32];
  const int tid = threadIdx.x;
  const int w = tid >> 6, lane = tid & 63;
  const int wr = w >> 1, wc = w & 1;
  const int row0 = blockIdx.x * 128, col0 = blockIdx.y * 128;
  f32x4 acc[4][4];
#pragma unroll
  for (int m = 0; m < 4; ++m)
#pragma unroll
    for (int n = 0; n < 4; ++n) acc[m][n] = (f32x4){0.f, 0.f, 0.f, 0.f};

  const int rstage = (lane >> 2);
  const int cstage = (lane & 3) * 8;

  for (int kt = 0; kt < RANKz / 32; ++kt) {
    const int k0 = kt * 32;
#pragma unroll
    for (int i = 0; i < 2; ++i) {
      const int chunk = i * 4 + w;
      const int r = chunk * 16 + rstage;
      const unsigned short* ga = A  + (size_t)(row0 + r) * RANKz + k0 + cstage;
      const unsigned short* gb = Bm + (size_t)(col0 + r) * RANKz + k0 + cstage;
      __builtin_amdgcn_global_load_lds((const __attribute__((address_space(1))) void*)ga,
                                       (__attribute__((address_space(3))) void*)&As[chunk * 512], 16, 0, 0);
      __builtin_amdgcn_global_load_lds((const __attribute__((address_space(1))) void*)gb,
                                       (__attribute__((address_space(3))) void*)&Bs[chunk * 512], 16, 0, 0);
    }
    __syncthreads();
    const int klo = (lane >> 4) * 8;
    bf16x8 af[4], bfr[4];
#pragma unroll
    for (int m = 0; m < 4; ++m)
      af[m] = *(const bf16x8*)&As[(wr * 64 + m * 16 + (lane & 15)) * 32 + klo];
#pragma unroll
    for (int n = 0; n < 4; ++n)
      bfr[n] = *(const bf16x8*)&Bs[(wc * 64 + n * 16 + (lane & 15)) * 32 + klo];
#pragma unroll
    for (int m = 0; m < 4; ++m)
#pragma unroll
      for (int n = 0; n < 4; ++n)
        acc[m][n] = __builtin_amdgcn_mfma_f32_16x16x32_bf16(af[m], bfr[n], acc[m][n], 0, 0, 0);
    __syncthreads();
  }
  const int cb = col0 + wc * 64 + (lane & 15);
  const int rb = row0 + wr * 64 + (lane >> 4) * 4;
#pragma unroll
  for (int m = 0; m < 4; ++m)
#pragma unroll
    for (int n = 0; n < 4; ++n)
#pragma unroll
      for (int j = 0; j < 4; ++j)
        C[(size_t)(rb + m * 16 + j) * 4096 + (cb + n * 16)] = f2b(acc[m][n][j]);
}

// ---------------------------------------------------------------- stage 2: MFMA attention
// grid (8 qtiles x 64 bh), 256 thr = 4 waves; wave owns 32 q-rows (2 m-halves of 16).
// KV tile = 64. Fragment conventions identical to gemm_kv_bf16 (validated):
//   A/B operand: elem [lane&15][(lane>>4)*8+j];  C/D: col=lane&15, row=(lane>>4)*4+j
__global__ __launch_bounds__(256, 2)
void mla_attn_mfma(const float* __restrict__ q,
                   const unsigned short* __restrict__ kvb,   // [T][16*256] bf16
                   const float* __restrict__ ropek,          // [T][64] fp32
                   float* __restrict__ out) {                // [T][16][128] fp32
  __shared__ unsigned short Ks[64][200];   // K tile (128 nope + 64 rope), pad->2-way max
  __shared__ unsigned short Vt[128][72];   // V transposed [d][k]
  __shared__ unsigned short Ps[4][16][72]; // per-wave P round-trip

  const int tid = threadIdx.x;
  const int w = tid >> 6, lane = tid & 63;
  const int lr = lane & 15, lg = lane >> 4;
  const int qt = blockIdx.x, bh = blockIdx.y;
  const int bat = bh >> 4, h = bh & 15;
  const int qbase = qt * 128;

  // ---- Q fragments, prescaled by SCALE, bf16, in registers
  bf16x8 qf[2][6];
#pragma unroll
  for (int mh = 0; mh < 2; ++mh) {
    const int qrow = qbase + w * 32 + mh * 16 + lr;
    const float* qp = q + ((size_t)(bat * Sz + qrow) * Hz + h) * 192 + lg * 8;
#pragma unroll
    for (int ks = 0; ks < 6; ++ks) {
      float4 a = *(const float4*)(qp + ks * 32);
      float4 b = *(const float4*)(qp + ks * 32 + 4);
      union { bf16x8 v; unsigned short u[8]; } t;
      t.u[0] = f2b(a.x * SCALEf); t.u[1] = f2b(a.y * SCALEf);
      t.u[2] = f2b(a.z * SCALEf); t.u[3] = f2b(a.w * SCALEf);
      t.u[4] = f2b(b.x * SCALEf); t.u[5] = f2b(b.y * SCALEf);
      t.u[6] = f2b(b.z * SCALEf); t.u[7] = f2b(b.w * SCALEf);
      qf[mh][ks] = t.v;
    }
  }

  f32x4 acc[2][8];
#pragma unroll
  for (int mh = 0; mh < 2; ++mh)
#pragma unroll
    for (int n = 0; n < 8; ++n) acc[mh][n] = (f32x4){0.f, 0.f, 0.f, 0.f};
  float m_run[2][4], l_run[2][4];
#pragma unroll
  for (int mh = 0; mh < 2; ++mh)
#pragma unroll
    for (int j = 0; j < 4; ++j) { m_run[mh][j] = -1e30f; l_run[mh][j] = 0.f; }

  const int ntiles = 2 * qt + 2;
  for (int t = 0; t < ntiles; ++t) {
    __syncthreads();   // all waves done reading previous tile
    const int ks0 = t * 64;
    const unsigned short* kvp = kvb + ((size_t)(bat * Sz + ks0) * Hz + h) * 256;

    { // ---- stage K nope: 64 rows x 128 bf16 (1024 16B chunks)
      int task = tid;
#pragma unroll
      for (int i = 0; i < 4; ++i, task += 256) {
        const int r = task >> 4, c = task & 15;
        *(uint4*)&Ks[r][c * 8] = *(const uint4*)&kvp[(size_t)r * 4096 + c * 8];
      }
      // ---- stage rope: 64 rows x 64 fp32 -> bf16 (512 8-elem chunks)
      task = tid;
#pragma unroll
      for (int i = 0; i < 2; ++i, task += 256) {
        const int r = task >> 3, c = task & 7;
        const float* rp = ropek + (size_t)(bat * Sz + ks0 + r) * 64 + c * 8;
        float4 a = *(const float4*)rp;
        float4 b = *(const float4*)(rp + 4);
        union { uint4 v; unsigned short u[8]; } o;
        o.u[0] = f2b(a.x); o.u[1] = f2b(a.y); o.u[2] = f2b(a.z); o.u[3] = f2b(a.w);
        o.u[4] = f2b(b.x); o.u[5] = f2b(b.y); o.u[6] = f2b(b.z); o.u[7] = f2b(b.w);
        *(uint4*)&Ks[r][128 + c * 8] = o.v;
      }
      // ---- stage V transposed: Vt[d][k] = V[k][d]; pack k-pairs into words
      task = tid;
#pragma unroll
      for (int i = 0; i < 2; ++i, task += 256) {
        const int kp = task & 31, dc = task >> 5;   // kp: row-pair, dc: 8-wide d chunk
        const int k0 = kp * 2, d0 = dc * 8;
        union { uint4 v; unsigned short u[8]; } r0, r1;
        r0.v = *(const uint4*)&kvp[(size_t)k0 * 4096 + 128 + d0];
        r1.v = *(const uint4*)&kvp[(size_t)(k0 + 1) * 4096 + 128 + d0];
#pragma unroll
        for (int jj = 0; jj < 8; ++jj) {
          const uint32_t pk = (uint32_t)r0.u[jj] | ((uint32_t)r1.u[jj] << 16);
          *(uint32_t*)&Vt[d0 + jj][k0] = pk;
        }
      }
    }
    __syncthreads();

#pragma unroll
    for (int mh = 0; mh < 2; ++mh) {
      const int row_min = qbase + w * 32 + mh * 16;
      if (ks0 > row_min + 15) continue;   // fully masked, wave-uniform

      // ---- QK^T: S[16 q][64 k], contraction over d=192
      f32x4 sfr[4];
#pragma unroll
      for (int n = 0; n < 4; ++n) sfr[n] = (f32x4){0.f, 0.f, 0.f, 0.f};
#pragma unroll
      for (int ks = 0; ks < 6; ++ks)
#pragma unroll
        for (int n = 0; n < 4; ++n) {
          bf16x8 bk = *(const bf16x8*)&Ks[n * 16 + lr][ks * 32 + lg * 8];
          sfr[n] = __builtin_amdgcn_mfma_f32_16x16x32_bf16(qf[mh][ks], bk, sfr[n], 0, 0, 0);
        }

      // ---- causal mask (only on diagonal tiles)
      float sv[4][4];
      const bool edge = (ks0 + 63 > row_min);
#pragma unroll
      for (int n = 0; n < 4; ++n)
#pragma unroll
        for (int j = 0; j < 4; ++j) {
          float s = sfr[n][j];
          if (edge && (ks0 + n * 16 + lr > row_min + lg * 4 + j)) s = -1e30f;
          sv[n][j] = s;
        }

      // ---- online softmax; row = 16-lane group, reduce via shfl_xor 1/2/4/8
      float mxj[4];
#pragma unroll
      for (int j = 0; j < 4; ++j)
        mxj[j] = fmaxf(fmaxf(sv[0][j], sv[1][j]), fmaxf(sv[2][j], sv[3][j]));
#pragma unroll
      for (int off = 1; off < 16; off <<= 1)
#pragma unroll
        for (int j = 0; j < 4; ++j) mxj[j] = fmaxf(mxj[j], __shfl_xor(mxj[j], off));

      float nm[4], cr[4];
#pragma unroll
      for (int j = 0; j < 4; ++j) {
        nm[j] = fmaxf(m_run[mh][j], mxj[j]);
        cr[j] = __expf(m_run[mh][j] - nm[j]);
        m_run[mh][j] = nm[j];
      }
      float p[4][4], ts[4];
#pragma unroll
      for (int n = 0; n < 4; ++n)
#pragma unroll
        for (int j = 0; j < 4; ++j) p[n][j] = __expf(sv[n][j] - nm[j]);
#pragma unroll
      for (int j = 0; j < 4; ++j) ts[j] = (p[0][j] + p[1][j]) + (p[2][j] + p[3][j]);
#pragma unroll
      for (int off = 1; off < 16; off <<= 1)
#pragma unroll
        for (int j = 0; j < 4; ++j) ts[j] += __shfl_xor(ts[j], off);
#pragma unroll
      for (int j = 0; j < 4; ++j) l_run[mh][j] = l_run[mh][j] * cr[j] + ts[j];

      // ---- rescale O accumulators
#pragma unroll
      for (int n = 0; n < 8; ++n)
#pragma unroll
        for (int j = 0; j < 4; ++j) acc[mh][n][j] *= cr[j];

      // ---- P -> LDS (bf16), reshape C-layout -> A-layout (same wave: ds order safe)
#pragma unroll
      for (int n = 0; n < 4; ++n)
#pragma unroll
        for (int j = 0; j < 4; ++j)
          Ps[w][lg * 4 + j][n * 16 + lr] = f2b(p[n][j]);

      // ---- PV: O[16 q][128 d] += P[16][64] * V[64][128]
#pragma unroll
      for (int kstep = 0; kstep < 2; ++kstep) {
        bf16x8 pa = *(const bf16x8*)&Ps[w][lr][kstep * 32 + lg * 8];
#pragma unroll
        for (int n = 0; n < 8; ++n) {
          bf16x8 bv = *(const bf16x8*)&Vt[n * 16 + lr][kstep * 32 + lg * 8];
          acc[mh][n] = __builtin_amdgcn_mfma_f32_16x16x32_bf16(pa, bv, acc[mh][n], 0, 0, 0);
        }
      }
    }
  }

  // ---- epilogue
#pragma unroll
  for (int mh = 0; mh < 2; ++mh) {
    float inv[4];
#pragma unroll
    for (int j = 0; j < 4; ++j) inv[j] = 1.0f / l_run[mh][j];
    const int qrow = qbase + w * 32 + mh * 16 + lg * 4;
#pragma unroll
    for (int n = 0; n < 8; ++n)
#pragma unroll
      for (int j = 0; j < 4; ++j)
        out[((size_t)(bat * Sz + qrow + j) * Hz + h) * 128 + n * 16 + lr] = acc[mh][n][j] * inv[j];
  }
}

// ---------------------------------------------------------------- launch
extern "C" void kernel_launch(void* const* d_in, const int* in_sizes, int n_in,
                              void* d_out, int out_size, void* d_ws, size_t ws_size,
                              hipStream_t stream) {
  const float* q    = (const float*)d_in[0];
  const float* ckv  = (const float*)d_in[1];
  const float* rope = (const float*)d_in[2];
  const float* wup  = (const float*)d_in[3];
  float* out = (float*)d_out;

  unsigned short* ckvb = (unsigned short*)d_ws;
  unsigned short* wupb = ckvb + (size_t)4096 * RANKz;
  unsigned short* kvb  = wupb + (size_t)4096 * RANKz;

  const int nvec = 4096 * RANKz / 4;
  cvt_bf16_kernel<<<(2 * nvec) / 256, 256, 0, stream>>>(ckv, ckvb, wup, wupb, nvec);

  dim3 gg(32, 32);
  gemm_kv_bf16<<<gg, 256, 0, stream>>>(ckvb, wupb, kvb);

  dim3 ga(8, 64);
  mla_attn_mfma<<<ga, 256, 0, stream>>>(q, kvb, rope, out);
}